// Round 1
// baseline (204.913 us; speedup 1.0000x reference)
//
#include <hip/hip_runtime.h>

#define W 320
#define H 96
#define FS 96
#define BS 8
#define NPLANES 9      // 1 + 2*4 levels
#define CH 24          // channels staged per LDS stage
#define NSTAGES 4      // FS / CH
#define PADW 328       // 4 guard + 320 + 4 guard
#define NTHREADS 192   // 3 waves; 160 active in compute (VX=2 over w=320)

__global__ __launch_bounds__(NTHREADS)
void cost_volume_kernel(const float* __restrict__ f1,
                        const float* __restrict__ f2,
                        float* __restrict__ out)
{
    __shared__ float sh[CH * PADW];  // 31,488 B -> 3 blocks/CU fits (94.5 KB)

    const int t   = threadIdx.x;
    const int row = blockIdx.x;      // 0..767 = (b, y)
    const int b   = row / H;
    const int y   = row % H;

    // Zero the +-4 guards once: 24 ch * 8 guards = 192 floats = NTHREADS.
    // Guards are never overwritten by staging, so once is enough.
    {
        const int c = t >> 3;
        const int g = t & 7;
        sh[c * PADW + (g < 4 ? g : 320 + g)] = 0.0f;
    }

    const float* f1row = f1 + ((size_t)(b * FS) * H + y) * W;  // + c*H*W per channel
    const float* f2row = f2 + ((size_t)(b * FS) * H + y) * W;

    float acc0[NPLANES], acc1[NPLANES];
#pragma unroll
    for (int p = 0; p < NPLANES; ++p) { acc0[p] = 0.f; acc1[p] = 0.f; }

    const int xi = t;        // compute lane: xi < 160
    const int x0 = 2 * xi;   // even -> 8B-aligned LDS window reads

    // div-free staging mapping: thread owns channel c = t>>3, sub-lane u = t&7,
    // loads float4 at xq = u + 8k for k = 0..9  (80 quads per channel row)
    const int sc = t >> 3;
    const int su = t & 7;

    for (int s = 0; s < NSTAGES; ++s) {
        const int c0 = s * CH;

        // ---- stage CH channels of the f2 row into LDS (float4 / b128) ----
        const float* f2c = f2row + (size_t)(c0 + sc) * (H * W);
#pragma unroll
        for (int k = 0; k < 10; ++k) {
            const int xq = su + 8 * k;
            const float4 v = *(const float4*)(f2c + 4 * xq);
            *(float4*)(&sh[sc * PADW + 4 + 4 * xq]) = v;
        }
        __syncthreads();

        // ---- compute: 24 channels, 10-wide f2 window, 18 FMAs/channel ----
        if (xi < 160) {
#pragma unroll 6
            for (int c = 0; c < CH; ++c) {
                const float2 a = *(const float2*)(f1row + (size_t)(c0 + c) * (H * W) + x0);
                // w[j] = f2[x0 - 4 + j], j=0..9 (zero-padded via guards)
                float wv[10];
#pragma unroll
                for (int k = 0; k < 5; ++k) {
                    const float2 v = *(const float2*)(&sh[c * PADW + x0 + 2 * k]);
                    wv[2 * k]     = v.x;
                    wv[2 * k + 1] = v.y;
                }
                // plane p <-> shift i = p-4; f2 col = x - i = x + 4 - p
#pragma unroll
                for (int p = 0; p < NPLANES; ++p) {
                    acc0[p] = fmaf(a.x, wv[8 - p], acc0[p]);
                    acc1[p] = fmaf(a.y, wv[9 - p], acc1[p]);
                }
            }
        }
        __syncthreads();  // protect sh before next stage overwrite
    }

    if (xi < 160) {
        const float scale = 1.0f / (float)FS;
#pragma unroll
        for (int p = 0; p < NPLANES; ++p) {
            float2 o;
            o.x = acc0[p] * scale;
            o.y = acc1[p] * scale;
            *(float2*)(out + (((size_t)(b * NPLANES + p)) * H + y) * W + x0) = o;
        }
    }
}

extern "C" void kernel_launch(void* const* d_in, const int* in_sizes, int n_in,
                              void* d_out, int out_size, void* d_ws, size_t ws_size,
                              hipStream_t stream) {
    (void)in_sizes; (void)n_in; (void)d_ws; (void)ws_size; (void)out_size;
    const float* f1 = (const float*)d_in[0];
    const float* f2 = (const float*)d_in[1];
    float* out = (float*)d_out;

    dim3 grid(BS * H);        // 768 blocks = 3 per CU exactly
    dim3 block(NTHREADS);
    cost_volume_kernel<<<grid, block, 0, stream>>>(f1, f2, out);
}